// Round 1
// baseline (364.843 us; speedup 1.0000x reference)
//
#include <hip/hip_runtime.h>
#include <math.h>

// Problem: B=1024 x[B,D], P=200 protos[P,D], subspaces U[P,D,S], D=512, S=64.
// out[b,p] = || (I - U_p U_p^T) (x_b - proto_p) ||_2
// Algebra: t = U^T x - U^T proto;  ||y||^2 = q - 2||t||^2 + t^T G t,
//          q = ||x||^2 - 2 x.proto + ||proto||^2,  G = U^T U.

#define NB 1024
#define NP 200
#define ND 512
#define NS 64

// workspace layout (float offsets); total 1038080 floats (~4.0 MB)
#define OFF_G   0           // [NP][NS*NS]
#define OFF_C   819200      // [NP][NS]
#define OFF_PN  832000      // [NP]
#define OFF_XN  832256      // [NB]
#define OFF_XP  833280      // [NB][NP]

// ---------------------------------------------------------------------------
// Kernel A: per-prototype precompute: G = U^T U, c = U^T proto, pn = ||proto||^2
// grid: NP blocks x 256 threads
// ---------------------------------------------------------------------------
__global__ __launch_bounds__(256) void k_proto_pre(
    const float* __restrict__ protos, const float* __restrict__ U,
    float* __restrict__ ws)
{
  const int p = blockIdx.x;
  __shared__ float Us[64][64];
  __shared__ float ps[64];
  const int tid = threadIdx.x;
  const int tx = tid & 15, ty = tid >> 4;
  float g[4][4] = {};
  float cacc = 0.f;
  float pnacc = 0.f;
  const float* Up = U + (size_t)p * ND * NS;
  const float* pr = protos + (size_t)p * ND;

  for (int d0 = 0; d0 < ND; d0 += 64) {
#pragma unroll
    for (int it = 0; it < 4; ++it) {
      int e = tid + it * 256;          // float4 index, 0..1023
      int dl = e >> 4, s4 = (e & 15) << 2;
      float4 v = *reinterpret_cast<const float4*>(Up + (size_t)(d0 + dl) * NS + s4);
      *reinterpret_cast<float4*>(&Us[dl][s4]) = v;
    }
    if (tid < 16) {
      *reinterpret_cast<float4*>(&ps[tid << 2]) =
          *reinterpret_cast<const float4*>(pr + d0 + (tid << 2));
    }
    __syncthreads();
#pragma unroll 4
    for (int dl = 0; dl < 64; ++dl) {
      float4 a = *reinterpret_cast<const float4*>(&Us[dl][ty << 2]);
      float4 b = *reinterpret_cast<const float4*>(&Us[dl][tx << 2]);
      float av[4] = {a.x, a.y, a.z, a.w};
      float bv[4] = {b.x, b.y, b.z, b.w};
#pragma unroll
      for (int i = 0; i < 4; ++i)
#pragma unroll
        for (int j = 0; j < 4; ++j)
          g[i][j] += av[i] * bv[j];
      if (tid < 64)  // wave 0 additionally accumulates c[s=tid]
        cacc += Us[dl][tid] * ps[dl];
    }
    if (tid >= 64 && tid < 128) {  // wave 1 accumulates ||proto||^2 (lane per d)
      float v = ps[tid - 64];
      pnacc += v * v;
    }
    __syncthreads();
  }

#pragma unroll
  for (int i = 0; i < 4; ++i) {
    float4 v = make_float4(g[i][0], g[i][1], g[i][2], g[i][3]);
    *reinterpret_cast<float4*>(ws + OFF_G + (size_t)p * NS * NS +
                               (size_t)((ty << 2) + i) * NS + (tx << 2)) = v;
  }
  if (tid < 64) ws[OFF_C + p * NS + tid] = cacc;
  if (tid >= 64 && tid < 128) {
#pragma unroll
    for (int m = 1; m <= 32; m <<= 1) pnacc += __shfl_xor(pnacc, m);
    if (tid == 64) ws[OFF_PN + p] = pnacc;
  }
}

// ---------------------------------------------------------------------------
// Kernel B: XP[b,p] = x_b . proto_p  and  xn[b] = ||x_b||^2
// grid: (NB/128, NP/8) x 256 threads. 128 rows x 8 protos per block.
// ---------------------------------------------------------------------------
__global__ __launch_bounds__(256) void k_xp(
    const float* __restrict__ x, const float* __restrict__ protos,
    float* __restrict__ ws)
{
  const int b0 = blockIdx.x * 128;
  const int p0 = blockIdx.y * 8;
  __shared__ float xs[64][132];   // [k][r], pad 132 keeps 16B-aligned rows
  __shared__ float ps2[8][64];
  const int tid = threadIdx.x;
  const int pp = tid >> 5, rx = tid & 31;   // proto, row-group
  float acc[4] = {0.f, 0.f, 0.f, 0.f};
  float xnacc[4] = {0.f, 0.f, 0.f, 0.f};

  for (int k0 = 0; k0 < ND; k0 += 64) {
#pragma unroll
    for (int it = 0; it < 8; ++it) {
      int r = (tid >> 4) + (it << 4);
      int kb = (tid & 15) << 2;
      float4 v = *reinterpret_cast<const float4*>(x + (size_t)(b0 + r) * ND + k0 + kb);
      xs[kb + 0][r] = v.x; xs[kb + 1][r] = v.y;
      xs[kb + 2][r] = v.z; xs[kb + 3][r] = v.w;
    }
    if (tid < 128) {
      int prw = tid >> 4, k4 = (tid & 15) << 2;
      *reinterpret_cast<float4*>(&ps2[prw][k4]) =
          *reinterpret_cast<const float4*>(protos + (size_t)(p0 + prw) * ND + k0 + k4);
    }
    __syncthreads();
#pragma unroll 8
    for (int k = 0; k < 64; ++k) {
      float pv = ps2[pp][k];
      float4 xv = *reinterpret_cast<const float4*>(&xs[k][rx << 2]);
      acc[0] += xv.x * pv; acc[1] += xv.y * pv;
      acc[2] += xv.z * pv; acc[3] += xv.w * pv;
      xnacc[0] += xv.x * xv.x; xnacc[1] += xv.y * xv.y;
      xnacc[2] += xv.z * xv.z; xnacc[3] += xv.w * xv.w;
    }
    __syncthreads();
  }

  const int p = p0 + pp;
#pragma unroll
  for (int i = 0; i < 4; ++i) {
    int b = b0 + (rx << 2) + i;
    ws[OFF_XP + (size_t)b * NP + p] = acc[i];
  }
  if (pp == 0) {
#pragma unroll
    for (int i = 0; i < 4; ++i)
      ws[OFF_XN + b0 + (rx << 2) + i] = xnacc[i];  // duplicate across p-tiles: benign
  }
}

// ---------------------------------------------------------------------------
// Kernel C: main. Per (p, 128-row tile): T = X_tile @ U_p; t = T - c;
// H = t @ G; out = sqrt(q - 2||t||^2 + sum(H*t))
// grid: (NB/128, NP) x 256 threads (16x16). ~74 KB LDS -> 2 blocks/CU.
// ---------------------------------------------------------------------------
__global__ __launch_bounds__(256) void k_main(
    const float* __restrict__ x, const float* __restrict__ U,
    const float* __restrict__ ws, float* __restrict__ out)
{
  const int p = blockIdx.y;
  const int b0 = blockIdx.x * 128;
  __shared__ float xs[32][132];   // [k][r]
  __shared__ float us[32][68];    // [k][s]
  __shared__ float gs[64][64];    // G
  __shared__ float tst[64][132];  // T transposed: [s][r]
  __shared__ float cs[64];
  const int tid = threadIdx.x;
  const int tx = tid & 15, ty = tid >> 4;

  // load G + c early (own LDS region; ordered by first barrier in k-loop)
  const float* Gp = ws + OFF_G + (size_t)p * NS * NS;
#pragma unroll
  for (int it = 0; it < 4; ++it) {
    int e = tid + it * 256;       // float4 index, 0..1023
    int s1 = e >> 4, s24 = (e & 15) << 2;
    *reinterpret_cast<float4*>(&gs[s1][s24]) =
        *reinterpret_cast<const float4*>(Gp + ((size_t)e << 2));
  }
  if (tid < 16)
    *reinterpret_cast<float4*>(&cs[tid << 2]) =
        *reinterpret_cast<const float4*>(ws + OFF_C + p * NS + (tid << 2));

  // -------- GEMM1: T[r][s] = sum_d X[b0+r][d] * U[d][s]; 8x4 per thread ----
  float acc[8][4] = {};
  const float* Up = U + (size_t)p * ND * NS;
  for (int k0 = 0; k0 < ND; k0 += 32) {
#pragma unroll
    for (int it = 0; it < 4; ++it) {
      int r = (tid >> 3) + (it << 5);
      int kb = (tid & 7) << 2;
      float4 v = *reinterpret_cast<const float4*>(x + (size_t)(b0 + r) * ND + k0 + kb);
      xs[kb + 0][r] = v.x; xs[kb + 1][r] = v.y;
      xs[kb + 2][r] = v.z; xs[kb + 3][r] = v.w;
    }
#pragma unroll
    for (int it = 0; it < 2; ++it) {
      int k = (tid >> 4) + (it << 4);
      int s4 = (tid & 15) << 2;
      *reinterpret_cast<float4*>(&us[k][s4]) =
          *reinterpret_cast<const float4*>(Up + (size_t)(k0 + k) * NS + s4);
    }
    __syncthreads();
#pragma unroll 4
    for (int k = 0; k < 32; ++k) {
      float4 xa = *reinterpret_cast<const float4*>(&xs[k][ty << 3]);
      float4 xb = *reinterpret_cast<const float4*>(&xs[k][(ty << 3) + 4]);
      float4 uv = *reinterpret_cast<const float4*>(&us[k][tx << 2]);
      float xr[8] = {xa.x, xa.y, xa.z, xa.w, xb.x, xb.y, xb.z, xb.w};
      float uj[4] = {uv.x, uv.y, uv.z, uv.w};
#pragma unroll
      for (int i = 0; i < 8; ++i)
#pragma unroll
        for (int j = 0; j < 4; ++j)
          acc[i][j] += xr[i] * uj[j];
    }
    __syncthreads();
  }

  // -------- t = T - c, stored transposed ----------------------------------
#pragma unroll
  for (int j = 0; j < 4; ++j) {
    float cj = cs[(tx << 2) + j];
#pragma unroll
    for (int i = 0; i < 8; ++i)
      tst[(tx << 2) + j][(ty << 3) + i] = acc[i][j] - cj;
  }
  __syncthreads();

  // -------- GEMM2: H[r][s2] = sum_s1 t[r][s1] * G[s1][s2] -----------------
  float h[8][4] = {};
#pragma unroll 4
  for (int k = 0; k < 64; ++k) {
    float4 ta = *reinterpret_cast<const float4*>(&tst[k][ty << 3]);
    float4 tb = *reinterpret_cast<const float4*>(&tst[k][(ty << 3) + 4]);
    float4 gv = *reinterpret_cast<const float4*>(&gs[k][tx << 2]);
    float tr[8] = {ta.x, ta.y, ta.z, ta.w, tb.x, tb.y, tb.z, tb.w};
    float gj[4] = {gv.x, gv.y, gv.z, gv.w};
#pragma unroll
    for (int i = 0; i < 8; ++i)
#pragma unroll
      for (int j = 0; j < 4; ++j)
        h[i][j] += tr[i] * gj[j];
  }

  // -------- tgt = sum_s2 H*t, tn = ||t||^2, reduce over tx ----------------
  float tgt[8], tn[8];
#pragma unroll
  for (int i = 0; i < 8; ++i) { tgt[i] = 0.f; tn[i] = 0.f; }
#pragma unroll
  for (int i = 0; i < 8; ++i)
#pragma unroll
    for (int j = 0; j < 4; ++j) {
      float tv = tst[(tx << 2) + j][(ty << 3) + i];
      tgt[i] += h[i][j] * tv;
      tn[i] += tv * tv;
    }
#pragma unroll
  for (int m = 1; m <= 8; m <<= 1) {
#pragma unroll
    for (int i = 0; i < 8; ++i) {
      tgt[i] += __shfl_xor(tgt[i], m);
      tn[i] += __shfl_xor(tn[i], m);
    }
  }

  if (tx == 0) {
    float pnv = ws[OFF_PN + p];
#pragma unroll
    for (int i = 0; i < 8; ++i) {
      int b = b0 + (ty << 3) + i;
      float q = ws[OFF_XN + b] - 2.f * ws[OFF_XP + (size_t)b * NP + p] + pnv;
      float v = q - 2.f * tn[i] + tgt[i];
      out[(size_t)b * NP + p] = sqrtf(fmaxf(v, 0.f));
    }
  }
}

// ---------------------------------------------------------------------------
extern "C" void kernel_launch(void* const* d_in, const int* in_sizes, int n_in,
                              void* d_out, int out_size, void* d_ws, size_t ws_size,
                              hipStream_t stream) {
  const float* x      = (const float*)d_in[0];
  const float* protos = (const float*)d_in[1];
  const float* U      = (const float*)d_in[2];
  float* out = (float*)d_out;
  float* ws  = (float*)d_ws;   // needs 1038080 floats (~4.0 MB)

  k_proto_pre<<<dim3(NP), dim3(256), 0, stream>>>(protos, U, ws);
  k_xp<<<dim3(NB / 128, NP / 8), dim3(256), 0, stream>>>(x, protos, ws);
  k_main<<<dim3(NB / 128, NP), dim3(256), 0, stream>>>(x, U, ws, out);
}

// Round 3
// 145.330 us; speedup vs baseline: 2.5104x; 2.5104x over previous
//
#include <hip/hip_runtime.h>
#include <math.h>

// Problem: B=1024 x[B,D], P=200 protos[P,D], U[P,D,S], D=512, S=64.
// out[b,p] = || (I - U_p U_p^T)(x_b - proto_p) ||
// Algebra: t = U^T x - c, c = U^T proto; ||y||^2 = q - 2||t||^2 + t^T G t,
//          q = ||x||^2 - 2 x.proto + ||proto||^2, G = U^T U.
// bf16 MFMA for GEMM1 (X @ [U | proto]) and the Gram matrix; fp32 VALU for
// the small quadratic-form epilogue (accuracy headroom: threshold = 2%).

#define NB 1024
#define NP 200
#define ND 512
#define NS 64
#define NS5 80   // 64 U-cols + proto col + 15 zero pad (5 MFMA col-tiles)

// ws float offsets; total 5,191,424 floats = 19.8 MB
#define OFF_G   0           // [200][64][64] fp32 Gram
#define OFF_C   819200      // [200][64]    c = U^T proto
#define OFF_PN  832000      // [200]        ||proto||^2
#define OFF_XN  832256      // [1024]       ||x||^2 (fp32 exact)
#define OFF_XB  833280      // bf16 [1024][512]      (262144 floats)
#define OFF_UB  1095424     // bf16 [200][80][512]   (4096000 floats)

typedef __attribute__((ext_vector_type(8))) short bf16x8;
typedef __attribute__((ext_vector_type(8))) unsigned short ushort8;
typedef __attribute__((ext_vector_type(4))) float f32x4;

__device__ __forceinline__ unsigned short f2bf(float f) {
  unsigned int u = __float_as_uint(f);
  u += 0x7fffu + ((u >> 16) & 1u);   // round-to-nearest-even
  return (unsigned short)(u >> 16);
}

// ---------------------------------------------------------------------------
// Xb = bf16(x), xn = ||x||^2.  grid 256 x 256thr (1 row per wave)
// ---------------------------------------------------------------------------
__global__ __launch_bounds__(256) void k_conv_x(const float* __restrict__ x,
                                                float* __restrict__ ws) {
  const int tid = threadIdx.x, l = tid & 63, w = tid >> 6;
  const int b = blockIdx.x * 4 + w;
  const float* src = x + (size_t)b * ND + l * 8;
  float4 v0 = *(const float4*)(src);
  float4 v1 = *(const float4*)(src + 4);
  ushort8 o;
  o[0]=f2bf(v0.x); o[1]=f2bf(v0.y); o[2]=f2bf(v0.z); o[3]=f2bf(v0.w);
  o[4]=f2bf(v1.x); o[5]=f2bf(v1.y); o[6]=f2bf(v1.z); o[7]=f2bf(v1.w);
  *(ushort8*)((unsigned short*)(ws + OFF_XB) + (size_t)b * ND + l * 8) = o;
  float s = v0.x*v0.x + v0.y*v0.y + v0.z*v0.z + v0.w*v0.w
          + v1.x*v1.x + v1.y*v1.y + v1.z*v1.z + v1.w*v1.w;
#pragma unroll
  for (int m = 1; m < 64; m <<= 1) s += __shfl_xor(s, m);
  if (l == 0) ws[OFF_XN + b] = s;
}

// ---------------------------------------------------------------------------
// Ub rows 0..63: U^T transposed to [p][s][d] bf16 via LDS tile.
// grid (8, 200) x 256thr, 64 d x 64 s per block.
// ---------------------------------------------------------------------------
__global__ __launch_bounds__(256) void k_conv_u(const float* __restrict__ U,
                                                float* __restrict__ ws) {
  const int d0 = blockIdx.x * 64;
  const int p  = blockIdx.y;
  __shared__ float ts[64][68];
  const int tid = threadIdx.x;
  {
    const int dd = tid >> 4, s4 = (tid & 15) << 2;
#pragma unroll
    for (int i = 0; i < 4; ++i)
      *(float4*)&ts[dd + i*16][s4] =
          *(const float4*)(U + ((size_t)p * ND + d0 + dd + i*16) * NS + s4);
  }
  __syncthreads();
  const int s = tid >> 2, j = tid & 3;
  unsigned short* dst = (unsigned short*)(ws + OFF_UB) +
                        ((size_t)p * NS5 + s) * ND + d0 + j * 16;
  ushort8 o0, o1;
#pragma unroll
  for (int i = 0; i < 8; ++i) o0[i] = f2bf(ts[j*16 + i][s]);
#pragma unroll
  for (int i = 0; i < 8; ++i) o1[i] = f2bf(ts[j*16 + 8 + i][s]);
  *(ushort8*)dst = o0;
  *(ushort8*)(dst + 8) = o1;
}

// ---------------------------------------------------------------------------
// Ub row 64 = bf16(proto); rows 65..79 = 0.  grid 200 x 256thr
// ---------------------------------------------------------------------------
__global__ __launch_bounds__(256) void k_conv_pz(const float* __restrict__ protos,
                                                 float* __restrict__ ws) {
  const int p = blockIdx.x, tid = threadIdx.x;
  unsigned short* ub = (unsigned short*)(ws + OFF_UB);
  float2 v = *(const float2*)(protos + (size_t)p * ND + tid * 2);
  unsigned short* d64 = ub + ((size_t)p * NS5 + 64) * ND + tid * 2;
  d64[0] = f2bf(v.x); d64[1] = f2bf(v.y);
  ushort8 z = {0,0,0,0,0,0,0,0};
#pragma unroll
  for (int i = 0; i < 4; ++i) {
    int g = tid + i * 256;
    if (g < 960)
      *(ushort8*)(ub + ((size_t)p * NS5 + 65) * ND + g * 8) = z;
  }
}

// ---------------------------------------------------------------------------
// k_gram: Ghat = Ub @ Ub^T via MFMA. Ghat[s1][s2] (s<64) = G, Ghat[s][64] = c,
// Ghat[64][64] = ||proto||^2.  grid 200 x 256thr. 80 KB LDS (whole Ut_p).
// ---------------------------------------------------------------------------
__global__ __launch_bounds__(256) void k_gram(float* __restrict__ ws) {
  const int p = blockIdx.x;
  __shared__ __align__(16) unsigned short ut[NS5 * ND];  // 80 KB, granule-swizzled
  const int tid = threadIdx.x, l = tid & 63, w = tid >> 6;
  const int lm = l & 15, lh = l >> 4;
  const unsigned short* ub =
      (const unsigned short*)(ws + OFF_UB) + (size_t)p * NS5 * ND;
  // stage: LDS granule f holds data granule (f&63)^(row&15) of row f>>6
#pragma unroll
  for (int i = 0; i < 20; ++i) {
    int f = tid + i * 256;
    int r = f >> 6;
    int gd = (f & 63) ^ (r & 15);
    *(ushort8*)(ut + (size_t)f * 8) = *(const ushort8*)(ub + (size_t)r * ND + gd * 8);
  }
  __syncthreads();
  // tiles: i1 in 0..3 x i2 in 0..4 (20) + (4,4) = 21; wave w takes tt = w+4k
  const int ntile = (w == 0) ? 6 : 5;
  for (int idx = 0; idx < ntile; ++idx) {
    int tt = (idx == 5) ? 20 : (w + 4 * idx);
    int i1 = (tt == 20) ? 4 : tt / 5;
    int i2 = (tt == 20) ? 4 : tt % 5;
    f32x4 g = {0.f, 0.f, 0.f, 0.f};
#pragma unroll
    for (int ks = 0; ks < 16; ++ks) {
      int sl = (ks * 4 + lh) ^ lm;
      bf16x8 a = *(const bf16x8*)(ut + (size_t)(i1*16 + lm) * ND + sl * 8);
      bf16x8 b = *(const bf16x8*)(ut + (size_t)(i2*16 + lm) * ND + sl * 8);
      g = __builtin_amdgcn_mfma_f32_16x16x32_bf16(a, b, g, 0, 0, 0);
    }
    int col = i2 * 16 + lm;
    int row0 = i1 * 16 + lh * 4;
    if (i1 < 4 && i2 < 4) {
#pragma unroll
      for (int q = 0; q < 4; ++q)
        ws[OFF_G + (size_t)p * 4096 + (size_t)(row0 + q) * 64 + col] = g[q];
    } else if (i1 < 4 && i2 == 4 && lm == 0) {
#pragma unroll
      for (int q = 0; q < 4; ++q) ws[OFF_C + p * 64 + row0 + q] = g[q];
    } else if (tt == 20 && l == 0) {
      ws[OFF_PN + p] = g[0];
    }
  }
}

// ---------------------------------------------------------------------------
// k_main: per (p, 128-row tile): T5 = Xb @ Ub_p^T via MFMA (cols 0..63 = t+c,
// col 64 = x.proto); then fp32 VALU: H = t@G, out = sqrt(q - 2||t||^2 + t.H).
// grid (8, 200) x 256thr. 70.4 KB LDS -> 2 blocks/CU.
// ---------------------------------------------------------------------------
__global__ __launch_bounds__(256) void k_main(float* __restrict__ ws,
                                              float* __restrict__ out) {
  const int p = blockIdx.y;
  const int b0 = blockIdx.x * 128;
  __shared__ __align__(16) char smem[70400];
  unsigned short* xs = (unsigned short*)smem;            // 128x128 bf16 swz (32KB)
  unsigned short* us = (unsigned short*)(smem + 32768);  // 80x128 bf16 swz (20KB)
  float* tst = (float*)smem;                             // [64][132] f32, overlays xs/us
  float* gs  = (float*)(smem + 53248);                   // [64][64] f32
  float* cs  = (float*)(smem + 69632);                   // [64]
  float* xps = (float*)(smem + 69888);                   // [128]
  const int tid = threadIdx.x, l = tid & 63, w = tid >> 6;
  const int lm = l & 15, lh = l >> 4;

  // G + c into LDS (visible after first barrier; used only after GEMM1)
#pragma unroll
  for (int it = 0; it < 4; ++it) {
    int e = tid + it * 256;
    *(float4*)(gs + e * 4) = *(const float4*)(ws + OFF_G + (size_t)p * 4096 + e * 4);
  }
  if (tid < 16)
    *(float4*)(cs + tid * 4) = *(const float4*)(ws + OFF_C + p * 64 + tid * 4);

  const unsigned short* Xb = (const unsigned short*)(ws + OFF_XB) + (size_t)b0 * ND;
  const unsigned short* Ub = (const unsigned short*)(ws + OFF_UB) + (size_t)p * NS5 * ND;

  // ---- GEMM1 (MFMA): wave w owns rows 32w..32w+31 (2 row-tiles) x 5 col-tiles
  f32x4 acc[2][5] = {};
  for (int k0 = 0; k0 < ND; k0 += 128) {
#pragma unroll
    for (int i = 0; i < 8; ++i) {            // xs: 2048 granules
      int f = tid + i * 256;
      int r = f >> 4;
      int gd = (f & 15) ^ (r & 15);
      *(ushort8*)(xs + (size_t)f * 8) =
          *(const ushort8*)(Xb + (size_t)r * ND + k0 + gd * 8);
    }
#pragma unroll
    for (int i = 0; i < 5; ++i) {            // us: 1280 granules
      int f = tid + i * 256;
      int r = f >> 4;
      int gd = (f & 15) ^ (r & 15);
      *(ushort8*)(us + (size_t)f * 8) =
          *(const ushort8*)(Ub + (size_t)r * ND + k0 + gd * 8);
    }
    __syncthreads();
#pragma unroll
    for (int ks = 0; ks < 4; ++ks) {
      int gsl = ((ks * 4 + lh) ^ lm) * 8;
      bf16x8 a0 = *(const bf16x8*)(xs + (size_t)((w*2+0)*16 + lm) * 128 + gsl);
      bf16x8 a1 = *(const bf16x8*)(xs + (size_t)((w*2+1)*16 + lm) * 128 + gsl);
#pragma unroll
      for (int j = 0; j < 5; ++j) {
        bf16x8 b = *(const bf16x8*)(us + (size_t)(j*16 + lm) * 128 + gsl);
        acc[0][j] = __builtin_amdgcn_mfma_f32_16x16x32_bf16(a0, b, acc[0][j], 0, 0, 0);
        acc[1][j] = __builtin_amdgcn_mfma_f32_16x16x32_bf16(a1, b, acc[1][j], 0, 0, 0);
      }
    }
    __syncthreads();
  }

  // ---- epilogue part 1: t = T - c stored transposed [s][r]; xp from col 64
#pragma unroll
  for (int i = 0; i < 2; ++i) {
    int rbase = (w * 2 + i) * 16 + lh * 4;
#pragma unroll
    for (int j = 0; j < 5; ++j) {
      f32x4 v = acc[i][j];
      if (j < 4) {
        int col = j * 16 + lm;
        float cj = cs[col];
#pragma unroll
        for (int q = 0; q < 4; ++q)
          tst[(size_t)col * 132 + rbase + q] = v[q] - cj;
      } else if (lm == 0) {
#pragma unroll
        for (int q = 0; q < 4; ++q) xps[rbase + q] = v[q];
      }
    }
  }
  __syncthreads();

  // ---- GEMM2 (fp32 VALU): H[r][s2] = sum_s1 t[r][s1] G[s1][s2]
  const int tx = tid & 15, ty = tid >> 4;
  float h[8][4] = {};
#pragma unroll 4
  for (int k = 0; k < 64; ++k) {
    float4 ta = *(const float4*)(tst + k * 132 + (ty << 3));
    float4 tb = *(const float4*)(tst + k * 132 + (ty << 3) + 4);
    float4 gv = *(const float4*)(gs + k * 64 + (tx << 2));
    float tr[8] = {ta.x, ta.y, ta.z, ta.w, tb.x, tb.y, tb.z, tb.w};
    float gj[4] = {gv.x, gv.y, gv.z, gv.w};
#pragma unroll
    for (int i = 0; i < 8; ++i)
#pragma unroll
      for (int j = 0; j < 4; ++j) h[i][j] += tr[i] * gj[j];
  }

  // ---- tgt = sum H*t, tn = ||t||^2, reduce over tx (16 lanes)
  float tgt[8], tn[8];
#pragma unroll
  for (int i = 0; i < 8; ++i) { tgt[i] = 0.f; tn[i] = 0.f; }
#pragma unroll
  for (int i = 0; i < 8; ++i)
#pragma unroll
    for (int j = 0; j < 4; ++j) {
      float tv = tst[(size_t)((tx << 2) + j) * 132 + (ty << 3) + i];
      tgt[i] += h[i][j] * tv;
      tn[i] += tv * tv;
    }
#pragma unroll
  for (int m = 1; m <= 8; m <<= 1)
#pragma unroll
    for (int i = 0; i < 8; ++i) {
      tgt[i] += __shfl_xor(tgt[i], m);
      tn[i] += __shfl_xor(tn[i], m);
    }

  if (tx == 0) {
    float pnv = ws[OFF_PN + p];
#pragma unroll
    for (int i = 0; i < 8; ++i) {
      int r = (ty << 3) + i;
      int b = b0 + r;
      float q = ws[OFF_XN + b] - 2.f * xps[r] + pnv;
      float v = q - 2.f * tn[i] + tgt[i];
      out[(size_t)b * NP + p] = sqrtf(fmaxf(v, 0.f));
    }
  }
}

// ---------------------------------------------------------------------------
extern "C" void kernel_launch(void* const* d_in, const int* in_sizes, int n_in,
                              void* d_out, int out_size, void* d_ws, size_t ws_size,
                              hipStream_t stream) {
  const float* x      = (const float*)d_in[0];
  const float* protos = (const float*)d_in[1];
  const float* U      = (const float*)d_in[2];
  float* out = (float*)d_out;
  float* ws  = (float*)d_ws;   // needs 5,191,424 floats (~19.8 MB)

  k_conv_x <<<dim3(NB / 4),      dim3(256), 0, stream>>>(x, ws);
  k_conv_u <<<dim3(8, NP),       dim3(256), 0, stream>>>(U, ws);
  k_conv_pz<<<dim3(NP),          dim3(256), 0, stream>>>(protos, ws);
  k_gram   <<<dim3(NP),          dim3(256), 0, stream>>>(ws);
  k_main   <<<dim3(NB / 128, NP), dim3(256), 0, stream>>>(ws, out);
}

// Round 4
// 133.731 us; speedup vs baseline: 2.7282x; 1.0867x over previous
//
#include <hip/hip_runtime.h>
#include <math.h>

// out[b,p] = || (I - U_p U_p^T)(x_b - proto_p) ||,  B=1024 P=200 D=512 S=64
// t = U^T x - c, c = U^T proto; ||y||^2 = q - 2||t||^2 + t^T G t,
// q = ||x||^2 - 2 x.proto + ||proto||^2, G = U^T U (symmetric).
// GEMM1 (X@[U|proto]) and GEMM2 (H=t@G) both bf16 MFMA; tn=||t||^2 fp32 exact.

#define NB 1024
#define NP 200
#define ND 512
#define NS 64
#define NS5 80   // 64 U-cols + proto col + 15 zero pad

// ws float offsets; total 4,781,768 floats = 19.1 MB
#define OFF_C   0          // fp32 [200][64]  c = U^T proto
#define OFF_PN  12800      // fp32 [200]      ||proto||^2
#define OFF_XN  13000      // fp32 [1024]     ||x||^2
#define OFF_GB  14024      // bf16 [200][64][64]  G
#define OFF_XB  423624     // bf16 [1024][512]
#define OFF_UB  685768     // bf16 [200][80][512] (U^T | proto | 0)

typedef __attribute__((ext_vector_type(8))) short bf16x8;
typedef __attribute__((ext_vector_type(8))) unsigned short ushort8;
typedef __attribute__((ext_vector_type(4))) float f32x4;

__device__ __forceinline__ unsigned short f2bf(float f) {
  unsigned int u = __float_as_uint(f);
  u += 0x7fffu + ((u >> 16) & 1u);   // RNE
  return (unsigned short)(u >> 16);
}
__device__ __forceinline__ float bf2f(unsigned short h) {
  return __uint_as_float(((unsigned int)h) << 16);
}

// ---------------------------------------------------------------------------
// k_pre: grid 232. Blocks 0..199: per-p transpose U -> Ub bf16 [s][d] (global
// + swizzled LDS), proto row 64, zero rows, then Gram via MFMA -> Gb/c/pn.
// Blocks 200..231: convert 32 rows of x -> Xb bf16 + ||x||^2.
// ---------------------------------------------------------------------------
__global__ __launch_bounds__(256) void k_pre(
    const float* __restrict__ x, const float* __restrict__ protos,
    const float* __restrict__ U, float* __restrict__ ws)
{
  const int bid = blockIdx.x;
  const int tid = threadIdx.x;
  if (bid >= NP) {
    // ---- x conversion: 32 rows per block, 8 threads/row ----
    const int b = (bid - NP) * 32 + (tid >> 3);
    const int cc = tid & 7;
    const float* src = x + (size_t)b * ND + cc * 64;
    unsigned short* dst = (unsigned short*)(ws + OFF_XB) + (size_t)b * ND + cc * 64;
    float s = 0.f;
#pragma unroll
    for (int i = 0; i < 8; ++i) {
      float4 v0 = *(const float4*)(src + i * 8);
      float4 v1 = *(const float4*)(src + i * 8 + 4);
      ushort8 o;
      o[0]=f2bf(v0.x); o[1]=f2bf(v0.y); o[2]=f2bf(v0.z); o[3]=f2bf(v0.w);
      o[4]=f2bf(v1.x); o[5]=f2bf(v1.y); o[6]=f2bf(v1.z); o[7]=f2bf(v1.w);
      *(ushort8*)(dst + i * 8) = o;
      s += v0.x*v0.x + v0.y*v0.y + v0.z*v0.z + v0.w*v0.w
         + v1.x*v1.x + v1.y*v1.y + v1.z*v1.z + v1.w*v1.w;
    }
    s += __shfl_xor(s, 1); s += __shfl_xor(s, 2); s += __shfl_xor(s, 4);
    if (cc == 0) ws[OFF_XN + b] = s;
    return;
  }
  // ---- prototype block ----
  const int p = bid;
  __shared__ __align__(16) unsigned short ut[NS5 * ND];  // 80 KB, granule-swizzled
  __shared__ float ts[32][68];                           // 8.7 KB transpose tile
  const int l = tid & 63, w = tid >> 6;
  const int lm = l & 15, lh = l >> 4;
  unsigned short* Ubg = (unsigned short*)(ws + OFF_UB) + (size_t)p * NS5 * ND;

  // 16 chunks of 32 d-rows: U[d][s] fp32 -> ut[s][d] bf16 (+ global Ub)
  for (int ch = 0; ch < 16; ++ch) {
    const int d0 = ch * 32;
    {
      const int dd = tid >> 3, c8 = (tid & 7) * 8;
      const float* srcu = U + ((size_t)p * ND + d0 + dd) * NS + c8;
      *(float4*)&ts[dd][c8]     = *(const float4*)(srcu);
      *(float4*)&ts[dd][c8 + 4] = *(const float4*)(srcu + 4);
    }
    __syncthreads();
    {
      const int s = tid >> 2, jj = tid & 3;
      ushort8 o;
#pragma unroll
      for (int i = 0; i < 8; ++i) o[i] = f2bf(ts[jj * 8 + i][s]);
      const int gd = ch * 4 + jj;            // data granule 0..63
      // LDS granule g holds data granule g^(row&15)  =>  place gd at gd^(s&15)
      *(ushort8*)(ut + ((size_t)s * 64 + (gd ^ (s & 15))) * 8) = o;
      *(ushort8*)(Ubg + (size_t)s * ND + gd * 8) = o;
    }
    __syncthreads();
  }
  // proto row 64 (swizzle mask = 64&15 = 0 -> linear) + zero rows 65..79
  if (tid < 64) {
    const float* pr = protos + (size_t)p * ND + tid * 8;
    float4 v0 = *(const float4*)(pr);
    float4 v1 = *(const float4*)(pr + 4);
    ushort8 o;
    o[0]=f2bf(v0.x); o[1]=f2bf(v0.y); o[2]=f2bf(v0.z); o[3]=f2bf(v0.w);
    o[4]=f2bf(v1.x); o[5]=f2bf(v1.y); o[6]=f2bf(v1.z); o[7]=f2bf(v1.w);
    *(ushort8*)(ut + ((size_t)64 * 64 + tid) * 8) = o;
    *(ushort8*)(Ubg + (size_t)64 * ND + tid * 8) = o;
  }
  {
    ushort8 z = {0,0,0,0,0,0,0,0};
#pragma unroll
    for (int i = 0; i < 4; ++i) {
      int f = tid + i * 256;
      if (f < 960) {   // 15 rows x 64 granules
        *(ushort8*)(ut + ((size_t)65 * 64 + f) * 8) = z;
        *(ushort8*)(Ubg + (size_t)65 * ND + f * 8) = z;
      }
    }
  }
  __syncthreads();

  // Gram: Ghat = Ub @ Ub^T via MFMA. 21 16x16 tiles over 5x5 grid (upper-left
  // 4x4 = G, col 4 = c, (4,4) diag = ||proto||^2).
  const int ntile = (w == 0) ? 6 : 5;
  for (int idx = 0; idx < ntile; ++idx) {
    int tt = (idx == 5) ? 20 : (w + 4 * idx);
    int i1 = (tt == 20) ? 4 : tt / 5;
    int i2 = (tt == 20) ? 4 : tt % 5;
    f32x4 g = {0.f, 0.f, 0.f, 0.f};
#pragma unroll
    for (int ks = 0; ks < 16; ++ks) {
      int sl = (ks * 4 + lh) ^ lm;
      bf16x8 a = *(const bf16x8*)(ut + ((size_t)(i1 * 16 + lm) * 64 + sl) * 8);
      bf16x8 b = *(const bf16x8*)(ut + ((size_t)(i2 * 16 + lm) * 64 + sl) * 8);
      g = __builtin_amdgcn_mfma_f32_16x16x32_bf16(a, b, g, 0, 0, 0);
    }
    int col = i2 * 16 + lm;
    int row0 = i1 * 16 + lh * 4;
    if (i1 < 4 && i2 < 4) {
      unsigned short* Gbg = (unsigned short*)(ws + OFF_GB) + (size_t)p * 4096;
#pragma unroll
      for (int q = 0; q < 4; ++q) Gbg[(size_t)(row0 + q) * 64 + col] = f2bf(g[q]);
    } else if (i1 < 4 && i2 == 4 && lm == 0) {
#pragma unroll
      for (int q = 0; q < 4; ++q) ws[OFF_C + p * 64 + row0 + q] = g[q];
    } else if (tt == 20 && l == 0) {
      ws[OFF_PN + p] = g[0];
    }
  }
}

// ---------------------------------------------------------------------------
// k_main: grid (8,200) x 256. GEMM1: T5 = Xb@Ub^T (MFMA, K-step 64, swizzled);
// epilogue: t=T-c -> tb bf16[128][72], tn fp32 from regs; GEMM2: H=tb@Gb
// (MFMA, G symmetric); tgt = sum H*t (VALU); out = sqrt(q - 2tn + tgt).
// LDS 35.8 KB -> 4 blocks/CU.
// ---------------------------------------------------------------------------
__global__ __launch_bounds__(256) void k_main(float* __restrict__ ws,
                                              float* __restrict__ out)
{
  const int p = blockIdx.y;
  const int b0 = blockIdx.x * 128;
  __shared__ __align__(16) char smem[36608];
  unsigned short* xs = (unsigned short*)smem;             // [128][64] swz, 16 KB
  unsigned short* us = (unsigned short*)(smem + 16384);   // [80][64] swz, 10 KB
  unsigned short* tb = (unsigned short*)smem;             // [128][72] bf16 overlay
  unsigned short* gs = (unsigned short*)(smem + 26624);   // [64][72] bf16 G
  float* cs  = (float*)(smem + 35840);                    // [64]
  float* xps = (float*)(smem + 36096);                    // [128]
  const int tid = threadIdx.x, l = tid & 63, w = tid >> 6;
  const int lm = l & 15, lh = l >> 4;

  // stage Gb -> gs (pad 72: 2-way banks), c -> cs (ordered by first barrier)
  {
    const unsigned short* Gbg = (const unsigned short*)(ws + OFF_GB) + (size_t)p * 4096;
#pragma unroll
    for (int i = 0; i < 2; ++i) {
      int f = tid + i * 256;              // 512 granules
      int r = f >> 3, g = f & 7;
      *(ushort8*)(gs + (size_t)r * 72 + g * 8) =
          *(const ushort8*)(Gbg + (size_t)r * 64 + g * 8);
    }
    if (tid < 16)
      *(float4*)(cs + tid * 4) = *(const float4*)(ws + OFF_C + p * 64 + tid * 4);
  }

  const unsigned short* Xb = (const unsigned short*)(ws + OFF_XB) + (size_t)b0 * ND;
  const unsigned short* Ub = (const unsigned short*)(ws + OFF_UB) + (size_t)p * NS5 * ND;

  // ---- GEMM1: wave w owns rows 32w..32w+31 (2 row-tiles) x 5 col-tiles ----
  f32x4 acc[2][5] = {};
  for (int k0 = 0; k0 < ND; k0 += 64) {
#pragma unroll
    for (int i = 0; i < 4; ++i) {          // xs: 1024 granules (8/row)
      int f = tid + i * 256;
      int r = f >> 3, g = f & 7;
      *(ushort8*)(xs + ((size_t)r * 8 + (g ^ (r & 7))) * 8) =
          *(const ushort8*)(Xb + (size_t)r * ND + k0 + g * 8);
    }
#pragma unroll
    for (int i = 0; i < 3; ++i) {          // us: 640 granules
      int f = tid + i * 256;
      if (f < 640) {
        int r = f >> 3, g = f & 7;
        *(ushort8*)(us + ((size_t)r * 8 + (g ^ (r & 7))) * 8) =
            *(const ushort8*)(Ub + (size_t)r * ND + k0 + g * 8);
      }
    }
    __syncthreads();
#pragma unroll
    for (int ks = 0; ks < 2; ++ks) {
      int slot = (ks * 4 + lh) ^ (lm & 7);
      bf16x8 a0 = *(const bf16x8*)(xs + (((size_t)((w*2+0)*16 + lm)) * 8 + slot) * 8);
      bf16x8 a1 = *(const bf16x8*)(xs + (((size_t)((w*2+1)*16 + lm)) * 8 + slot) * 8);
#pragma unroll
      for (int j = 0; j < 5; ++j) {
        bf16x8 b = *(const bf16x8*)(us + (((size_t)(j*16 + lm)) * 8 + slot) * 8);
        acc[0][j] = __builtin_amdgcn_mfma_f32_16x16x32_bf16(a0, b, acc[0][j], 0, 0, 0);
        acc[1][j] = __builtin_amdgcn_mfma_f32_16x16x32_bf16(a1, b, acc[1][j], 0, 0, 0);
      }
    }
    __syncthreads();
  }

  // ---- epilogue 1: t = acc - c -> tb bf16; tn (fp32, exact); xps ----
  float tn[2][4] = {};
#pragma unroll
  for (int i = 0; i < 2; ++i) {
    int rbase = (w * 2 + i) * 16 + lh * 4;
#pragma unroll
    for (int j = 0; j < 5; ++j) {
      f32x4 v = acc[i][j];
      if (j < 4) {
        int col = j * 16 + lm;
        float cj = cs[col];
#pragma unroll
        for (int q = 0; q < 4; ++q) {
          float t = v[q] - cj;
          tn[i][q] += t * t;
          tb[(size_t)(rbase + q) * 72 + col] = f2bf(t);
        }
      } else if (lm == 0) {
#pragma unroll
        for (int q = 0; q < 4; ++q) xps[rbase + q] = v[q];
      }
    }
  }
  __syncthreads();

  // ---- GEMM2: H = tb @ G (B-frag = G rows, symmetric) ----
  f32x4 acc2[2][4] = {};
#pragma unroll
  for (int ks = 0; ks < 2; ++ks) {
#pragma unroll
    for (int i = 0; i < 2; ++i) {
      bf16x8 a = *(const bf16x8*)(tb + (size_t)((w*2+i)*16 + lm) * 72 + ks*32 + lh*8);
#pragma unroll
      for (int j = 0; j < 4; ++j) {
        bf16x8 b = *(const bf16x8*)(gs + (size_t)(j*16 + lm) * 72 + ks*32 + lh*8);
        acc2[i][j] = __builtin_amdgcn_mfma_f32_16x16x32_bf16(a, b, acc2[i][j], 0, 0, 0);
      }
    }
  }

  // ---- tgt = sum_s2 H*t; reduce tgt,tn over lm; write out ----
  const float pnv = ws[OFF_PN + p];
#pragma unroll
  for (int i = 0; i < 2; ++i) {
    int rbase = (w * 2 + i) * 16 + lh * 4;
    float tgt[4] = {0.f, 0.f, 0.f, 0.f};
#pragma unroll
    for (int j = 0; j < 4; ++j) {
      int col = j * 16 + lm;
#pragma unroll
      for (int q = 0; q < 4; ++q)
        tgt[q] += acc2[i][j][q] * bf2f(tb[(size_t)(rbase + q) * 72 + col]);
    }
#pragma unroll
    for (int q = 0; q < 4; ++q) {
      float ta = tgt[q], tname = tn[i][q];
#pragma unroll
      for (int m = 1; m <= 8; m <<= 1) {
        ta += __shfl_xor(ta, m);
        tname += __shfl_xor(tname, m);
      }
      tgt[q] = ta; tn[i][q] = tname;
    }
    if (lm == 0) {
#pragma unroll
      for (int q = 0; q < 4; ++q) {
        int r = rbase + q;
        int bb = b0 + r;
        float qq = ws[OFF_XN + bb] - 2.f * xps[r] + pnv;
        float v = qq - 2.f * tn[i][q] + tgt[q];
        out[(size_t)bb * NP + p] = sqrtf(fmaxf(v, 0.f));
      }
    }
  }
}

// ---------------------------------------------------------------------------
extern "C" void kernel_launch(void* const* d_in, const int* in_sizes, int n_in,
                              void* d_out, int out_size, void* d_ws, size_t ws_size,
                              hipStream_t stream) {
  const float* x      = (const float*)d_in[0];
  const float* protos = (const float*)d_in[1];
  const float* U      = (const float*)d_in[2];
  float* out = (float*)d_out;
  float* ws  = (float*)d_ws;   // needs 4,781,768 floats (~19.1 MB)

  k_pre <<<dim3(NP + NB / 32), dim3(256), 0, stream>>>(x, protos, U, ws);
  k_main<<<dim3(NB / 128, NP), dim3(256), 0, stream>>>(ws, out);
}

// Round 6
// 128.694 us; speedup vs baseline: 2.8350x; 1.0391x over previous
//
#include <hip/hip_runtime.h>
#include <math.h>

// out[b,p] = || (I - U_p U_p^T)(x_b - proto_p) ||,  B=1024 P=200 D=512 S=64
// t = U^T x - c, c = U^T proto; ||y||^2 = q - 2||t||^2 + t^T G t,
// q = ||x||^2 - 2 x.proto + ||proto||^2, G = U^T U (symmetric).
// GEMM1 (X@[U|proto]) + GEMM2 (H=t@G) in bf16 MFMA; tn=||t||^2 fp32 exact.

#define NB 1024
#define NP 200
#define ND 512
#define NS 64
#define NS5 80   // 64 U-cols + proto col + 15 pad rows (never consumed)

// ws float offsets; total 4,785,864 floats (~19.2 MB) incl. 16-row overrun pad
#define OFF_C   0          // fp32 [200][64]  c = U^T proto
#define OFF_PN  12800      // fp32 [200]      ||proto||^2
#define OFF_XN  13000      // fp32 [1024]     ||x||^2
#define OFF_GB  14024      // bf16 [200][64][64]  G
#define OFF_XB  423624     // bf16 [1024][512]
#define OFF_UB  685768     // bf16 [200][80][512] (U^T | proto | junk)

typedef __attribute__((ext_vector_type(8))) short bf16x8;
typedef __attribute__((ext_vector_type(8))) unsigned short ushort8;
typedef __attribute__((ext_vector_type(4))) float f32x4;

__device__ __forceinline__ unsigned short f2bf(float f) {
  unsigned int u = __float_as_uint(f);
  u += 0x7fffu + ((u >> 16) & 1u);   // RNE
  return (unsigned short)(u >> 16);
}
__device__ __forceinline__ float bf2f(unsigned short h) {
  return __uint_as_float(((unsigned int)h) << 16);
}
// async global->LDS, 16B per lane; LDS dest = wave-uniform base + lane*16
__device__ __forceinline__ void gl_lds16(const void* g, void* l) {
  __builtin_amdgcn_global_load_lds(
      (const __attribute__((address_space(1))) unsigned int*)g,
      (__attribute__((address_space(3))) unsigned int*)l, 16, 0, 0);
}

// ---------------------------------------------------------------------------
// k_conv: grid 832. Blocks 0..799: transpose+convert U chunk (p = bid>>2,
// 128 d-rows) -> Ub bf16 [p][s][d] + proto row-64 segment. Blocks 800..831:
// convert 32 rows of x -> Xb bf16 + ||x||^2.
// ---------------------------------------------------------------------------
__global__ __launch_bounds__(256) void k_conv(
    const float* __restrict__ x, const float* __restrict__ protos,
    const float* __restrict__ U, float* __restrict__ ws)
{
  const int bid = blockIdx.x, tid = threadIdx.x;
  if (bid >= 800) {
    const int b = (bid - 800) * 32 + (tid >> 3);
    const int cc = tid & 7;
    const float* src = x + (size_t)b * ND + cc * 64;
    unsigned short* dst = (unsigned short*)(ws + OFF_XB) + (size_t)b * ND + cc * 64;
    float s = 0.f;
#pragma unroll
    for (int i = 0; i < 8; ++i) {
      float4 v0 = *(const float4*)(src + i * 8);
      float4 v1 = *(const float4*)(src + i * 8 + 4);
      ushort8 o;
      o[0]=f2bf(v0.x); o[1]=f2bf(v0.y); o[2]=f2bf(v0.z); o[3]=f2bf(v0.w);
      o[4]=f2bf(v1.x); o[5]=f2bf(v1.y); o[6]=f2bf(v1.z); o[7]=f2bf(v1.w);
      *(ushort8*)(dst + i * 8) = o;
      s += v0.x*v0.x + v0.y*v0.y + v0.z*v0.z + v0.w*v0.w
         + v1.x*v1.x + v1.y*v1.y + v1.z*v1.z + v1.w*v1.w;
    }
    s += __shfl_xor(s, 1); s += __shfl_xor(s, 2); s += __shfl_xor(s, 4);
    if (cc == 0) ws[OFF_XN + b] = s;
    return;
  }
  const int p = bid >> 2, d0 = (bid & 3) * 128;
  __shared__ unsigned short ts[128][66];   // bf16, pad 66: column reads 2-way
#pragma unroll
  for (int i = 0; i < 8; ++i) {
    int row = (tid >> 4) + i * 16;
    int col = (tid & 15) * 4;
    float4 v = *(const float4*)(U + ((size_t)p * ND + d0 + row) * NS + col);
    ts[row][col] = f2bf(v.x); ts[row][col+1] = f2bf(v.y);
    ts[row][col+2] = f2bf(v.z); ts[row][col+3] = f2bf(v.w);
  }
  __syncthreads();
  unsigned short* Ubg = (unsigned short*)(ws + OFF_UB) + (size_t)p * NS5 * ND;
#pragma unroll
  for (int i = 0; i < 4; ++i) {
    int f = tid + i * 256;               // 1024 granules: s = f>>4, g = f&15
    int s = f >> 4, g = f & 15;
    ushort8 o;
#pragma unroll
    for (int j = 0; j < 8; ++j) o[j] = ts[g * 8 + j][s];
    *(ushort8*)(Ubg + (size_t)s * ND + d0 + g * 8) = o;
  }
  if (tid < 16) {                        // proto row 64, this d-chunk
    const float* pr = protos + (size_t)p * ND + d0 + tid * 8;
    float4 v0 = *(const float4*)pr, v1 = *(const float4*)(pr + 4);
    ushort8 o;
    o[0]=f2bf(v0.x); o[1]=f2bf(v0.y); o[2]=f2bf(v0.z); o[3]=f2bf(v0.w);
    o[4]=f2bf(v1.x); o[5]=f2bf(v1.y); o[6]=f2bf(v1.z); o[7]=f2bf(v1.w);
    *(ushort8*)(Ubg + (size_t)64 * ND + d0 + tid * 8) = o;
  }
}

// ---------------------------------------------------------------------------
// k_gram: Ghat = Ub @ Ub^T via MFMA. 4x4 tiles -> Gb bf16; col 4 -> c fp32;
// (4,4) diag -> pn. grid 200 x 256. 80 KB LDS, granule-swizzled.
// ---------------------------------------------------------------------------
__global__ __launch_bounds__(256) void k_gram(float* __restrict__ ws) {
  const int p = blockIdx.x;
  __shared__ __align__(16) unsigned short ut[NS5 * ND];  // 80 KB
  const int tid = threadIdx.x, l = tid & 63, w = tid >> 6;
  const int lm = l & 15, lh = l >> 4;
  const unsigned short* ub =
      (const unsigned short*)(ws + OFF_UB) + (size_t)p * NS5 * ND;
  // LDS granule f holds data granule (f&63)^(row&15) of row f>>6
#pragma unroll
  for (int i = 0; i < 20; ++i) {
    int f = tid + i * 256;
    int r = f >> 6;
    int gd = (f & 63) ^ (r & 15);
    *(ushort8*)(ut + (size_t)f * 8) = *(const ushort8*)(ub + (size_t)r * ND + gd * 8);
  }
  __syncthreads();
  const int ntile = (w == 0) ? 6 : 5;
  for (int idx = 0; idx < ntile; ++idx) {
    int tt = (idx == 5) ? 20 : (w + 4 * idx);
    int i1 = (tt == 20) ? 4 : tt / 5;
    int i2 = (tt == 20) ? 4 : tt % 5;
    f32x4 g = {0.f, 0.f, 0.f, 0.f};
#pragma unroll
    for (int ks = 0; ks < 16; ++ks) {
      int sl = (ks * 4 + lh) ^ lm;
      bf16x8 a = *(const bf16x8*)(ut + ((size_t)(i1 * 16 + lm) * 64 + sl) * 8);
      bf16x8 b = *(const bf16x8*)(ut + ((size_t)(i2 * 16 + lm) * 64 + sl) * 8);
      g = __builtin_amdgcn_mfma_f32_16x16x32_bf16(a, b, g, 0, 0, 0);
    }
    int col = i2 * 16 + lm;
    int row0 = i1 * 16 + lh * 4;
    if (i1 < 4 && i2 < 4) {
      unsigned short* Gbg = (unsigned short*)(ws + OFF_GB) + (size_t)p * 4096;
#pragma unroll
      for (int q = 0; q < 4; ++q) Gbg[(size_t)(row0 + q) * 64 + col] = f2bf(g[q]);
    } else if (i1 < 4 && i2 == 4 && lm == 0) {
#pragma unroll
      for (int q = 0; q < 4; ++q) ws[OFF_C + p * 64 + row0 + q] = g[q];
    } else if (tt == 20 && l == 0) {
      ws[OFF_PN + p] = g[0];
    }
  }
}

// ---------------------------------------------------------------------------
// k_main: grid (200, 8) [bid = p + 200*rt -> all 8 row-tiles of p on one XCD].
// GEMM1 via global_load_lds double-buffered 2-phase pipeline (K-step 64);
// epilogue: t -> tb bf16, tn fp32; GEMM2 H = tb@Gb MFMA; out.
// LDS 58112 B -> 2 blocks/CU.
// ---------------------------------------------------------------------------
__global__ __launch_bounds__(256) void k_main(float* __restrict__ ws,
                                              float* __restrict__ out)
{
  const int p = blockIdx.x;
  const int b0 = blockIdx.y * 128;
  __shared__ __align__(16) char smem[58112];
  unsigned short* xs = (unsigned short*)smem;             // 2 x 1024 granules
  unsigned short* us = (unsigned short*)(smem + 32768);   // 2 x 768 granules
  unsigned short* tb = (unsigned short*)smem;             // [128][72] overlay
  unsigned short* gs = (unsigned short*)(smem + 18432);   // [64][72] overlay
  float* cs  = (float*)(smem + 57344);                    // [64] (not overlaid)
  float* xps = (float*)(smem + 57600);                    // [128]
  const int tid = threadIdx.x, l = tid & 63, w = tid >> 6;
  const int lm = l & 15, lh = l >> 4;

  const unsigned short* Xb = (const unsigned short*)(ws + OFF_XB) + (size_t)b0 * ND;
  const unsigned short* Ub = (const unsigned short*)(ws + OFF_UB) + (size_t)p * NS5 * ND;

  // stage one K-tile (7 calls/wave): LDS linear, swizzle on global source.
  // granule f: row r=f>>3, slot=f&7 holds data granule (slot^(r&7)) of row r.
  auto stage = [&](int buf, int k0) {
#pragma unroll
    for (int c = 0; c < 4; ++c) {        // xs: waves cover 1024 granules
      int f = w * 256 + c * 64 + l;
      int r = f >> 3, gd = (f & 7) ^ (r & 7);
      gl_lds16(Xb + (size_t)r * ND + k0 + gd * 8,
               xs + ((size_t)buf * 8192 + (w * 256 + c * 64) * 8));
    }
#pragma unroll
    for (int c = 0; c < 3; ++c) {        // us: 768 granules (rows 0..95; >79 junk)
      int f = w * 192 + c * 64 + l;
      int r = f >> 3, gd = (f & 7) ^ (r & 7);
      gl_lds16(Ub + (size_t)r * ND + k0 + gd * 8,
               us + ((size_t)buf * 6144 + (w * 192 + c * 64) * 8));
    }
  };

  stage(0, 0);
  if (tid < 16)
    *(float4*)(cs + tid * 4) = *(const float4*)(ws + OFF_C + p * 64 + tid * 4);
  asm volatile("s_waitcnt vmcnt(0) lgkmcnt(0)" ::: "memory");
  __builtin_amdgcn_s_barrier();

  // ---- GEMM1: wave w rows 32w..32w+31 (2 row-tiles) x 5 col-tiles ----
  f32x4 acc[2][5] = {};
  for (int it = 0; it < 8; ++it) {
    const int buf = it & 1;
    if (it < 7) stage(buf ^ 1, (it + 1) * 64);   // prefetch in flight over MFMA
    const unsigned short* xb = xs + buf * 8192;
    const unsigned short* ub2 = us + buf * 6144;
#pragma unroll
    for (int ks = 0; ks < 2; ++ks) {
      const int slot = (ks * 4 + lh) ^ (lm & 7);
      bf16x8 a0 = *(const bf16x8*)(xb + (((size_t)((w*2+0)*16 + lm)) * 8 + slot) * 8);
      bf16x8 a1 = *(const bf16x8*)(xb + (((size_t)((w*2+1)*16 + lm)) * 8 + slot) * 8);
#pragma unroll
      for (int j = 0; j < 5; ++j) {
        bf16x8 b = *(const bf16x8*)(ub2 + (((size_t)(j*16 + lm)) * 8 + slot) * 8);
        acc[0][j] = __builtin_amdgcn_mfma_f32_16x16x32_bf16(a0, b, acc[0][j], 0, 0, 0);
        acc[1][j] = __builtin_amdgcn_mfma_f32_16x16x32_bf16(a1, b, acc[1][j], 0, 0, 0);
      }
    }
    asm volatile("s_waitcnt vmcnt(0)" ::: "memory");
    __builtin_amdgcn_s_barrier();
  }

  // ---- stage Gb -> gs (overlay region, safe after final barrier) ----
  {
    const unsigned short* Gbg = (const unsigned short*)(ws + OFF_GB) + (size_t)p * 4096;
#pragma unroll
    for (int i = 0; i < 2; ++i) {
      int f = tid + i * 256;
      int r = f >> 3, g = f & 7;
      *(ushort8*)(gs + (size_t)r * 72 + g * 8) =
          *(const ushort8*)(Gbg + (size_t)r * 64 + g * 8);
    }
  }

  // ---- epilogue 1: t = acc - c -> tb bf16; tn fp32 exact; xps ----
  float tn[2][4] = {};
#pragma unroll
  for (int i = 0; i < 2; ++i) {
    int rbase = (w * 2 + i) * 16 + lh * 4;
#pragma unroll
    for (int j = 0; j < 5; ++j) {
      f32x4 v = acc[i][j];
      if (j < 4) {
        int col = j * 16 + lm;
        float cj = cs[col];
#pragma unroll
        for (int q = 0; q < 4; ++q) {
          float t = v[q] - cj;
          tn[i][q] += t * t;
          tb[(size_t)(rbase + q) * 72 + col] = f2bf(t);
        }
      } else if (lm == 0) {
#pragma unroll
        for (int q = 0; q < 4; ++q) xps[rbase + q] = v[q];
      }
    }
  }
  __syncthreads();

  // ---- GEMM2: H = tb @ G (B-frag = G rows, G symmetric) ----
  f32x4 acc2[2][4] = {};
#pragma unroll
  for (int ks = 0; ks < 2; ++ks) {
#pragma unroll
    for (int i = 0; i < 2; ++i) {
      bf16x8 a = *(const bf16x8*)(tb + (size_t)((w*2+i)*16 + lm) * 72 + ks*32 + lh*8);
#pragma unroll
      for (int j = 0; j < 4; ++j) {
        bf16x8 b = *(const bf16x8*)(gs + (size_t)(j*16 + lm) * 72 + ks*32 + lh*8);
        acc2[i][j] = __builtin_amdgcn_mfma_f32_16x16x32_bf16(a, b, acc2[i][j], 0, 0, 0);
      }
    }
  }

  // ---- tgt = sum_s2 H*t; reduce over lm; out = sqrt(q - 2tn + tgt) ----
  const float pnv = ws[OFF_PN + p];
#pragma unroll
  for (int i = 0; i < 2; ++i) {
    int rbase = (w * 2 + i) * 16 + lh * 4;
    float tgt[4] = {0.f, 0.f, 0.f, 0.f};
#pragma unroll
    for (int j = 0; j < 4; ++j) {
      int col = j * 16 + lm;
#pragma unroll
      for (int q = 0; q < 4; ++q)
        tgt[q] += acc2[i][j][q] * bf2f(tb[(size_t)(rbase + q) * 72 + col]);
    }
#pragma unroll
    for (int q = 0; q < 4; ++q) {
      float ta = tgt[q], tnv = tn[i][q];
#pragma unroll
      for (int m = 1; m <= 8; m <<= 1) {
        ta += __shfl_xor(ta, m);
        tnv += __shfl_xor(tnv, m);
      }
      tgt[q] = ta; tn[i][q] = tnv;
    }
    if (lm == 0) {
#pragma unroll
      for (int q = 0; q < 4; ++q) {
        int r = rbase + q;
        int bb = b0 + r;
        float qq = ws[OFF_XN + bb] - 2.f * xps[r] + pnv;
        float v = qq - 2.f * tn[i][q] + tgt[q];
        out[(size_t)bb * NP + p] = sqrtf(fmaxf(v, 0.f));
      }
    }
  }
}

// ---------------------------------------------------------------------------
extern "C" void kernel_launch(void* const* d_in, const int* in_sizes, int n_in,
                              void* d_out, int out_size, void* d_ws, size_t ws_size,
                              hipStream_t stream) {
  const float* x      = (const float*)d_in[0];
  const float* protos = (const float*)d_in[1];
  const float* U      = (const float*)d_in[2];
  float* out = (float*)d_out;
  float* ws  = (float*)d_ws;   // needs 4,785,864 floats (~19.2 MB)

  k_conv<<<dim3(832),     dim3(256), 0, stream>>>(x, protos, U, ws);
  k_gram<<<dim3(NP),      dim3(256), 0, stream>>>(ws);
  k_main<<<dim3(NP, 8),   dim3(256), 0, stream>>>(ws, out);
}